// Round 6
// baseline (4275.491 us; speedup 1.0000x reference)
//
#include <hip/hip_runtime.h>
#include <math.h>

#define T_LEN 8192
#define NUM_CH 64
#define HID 256
#define NUM_CLS 40
#define NUM_PROP 1024
#define NUM_PROP_AFTER 256
#define PROP_LEN 128
#define NGRP 8                // groups (one per XCD ideally)
#define GBLK 32               // blocks per group; block owns 8 hidden units
#define NBLK (NGRP * GBLK)    // 256 blocks, 1 per CU

typedef _Float16 h2_t __attribute__((ext_vector_type(2)));
union U32H2 { unsigned int u; h2_t h; };
union HU16 { _Float16 h; unsigned short u; };

#if defined(__has_builtin)
#if __has_builtin(__builtin_amdgcn_fdot2)
#define HAS_FDOT2 1
#endif
#endif

__device__ __forceinline__ float dot2f(unsigned int wa, unsigned int hb, float acc) {
    U32H2 a, b;
    a.u = wa;
    b.u = hb;
#ifdef HAS_FDOT2
    return __builtin_amdgcn_fdot2(a.h, b.h, acc, false);
#else
    return acc + (float)a.h[0] * (float)b.h[0] + (float)a.h[1] * (float)b.h[1];
#endif
}

__device__ __forceinline__ float dot8f(const uint4& w, const uint4& h, float acc) {
    acc = dot2f(w.x, h.x, acc);
    acc = dot2f(w.y, h.y, acc);
    acc = dot2f(w.z, h.z, acc);
    acc = dot2f(w.w, h.w, acc);
    return acc;
}

__device__ __forceinline__ float fsigmoid(float x) { return 1.0f / (1.0f + __expf(-x)); }
__device__ __forceinline__ float ftanh(float x) {
    float e = __expf(-2.0f * fabsf(x));
    float t = (1.0f - e) / (1.0f + e);
    return copysignf(t, x);
}

__device__ __forceinline__ unsigned int pk2(float a, float b) {
    h2_t h;
    h[0] = (_Float16)a;
    h[1] = (_Float16)b;
    U32H2 u;
    u.h = h;
    return u.u;
}

// ---------------------------------------------------------------------------
// Workspace layout (bytes):
//   0      : arrive counters, 8 x 256B
//   2048   : t0s (256 int)
//   4096   : WP packed f16 weights (327680 halves = 640 KB)
//   659456 : h_glob [2 parity][8 grp][32 s][256 u] halves = 256 KB
// ---------------------------------------------------------------------------

// Pack W f16: half-index ((b_loc*40 + i)*32 + q)*8 + j
//   i = ci*8 + gate*2 + up  (ci 0..4, gate 0..3, up 0..1)
//   q = cs*4 + p            (cs 0..7, p 0..3)
//   row R = gate*256 + b_loc*8 + p*2 + up ; k = (cs*5 + ci)*8 + j
// Also zeroes the arrive counters (runs before lstm on the same stream).
__global__ __launch_bounds__(256) void pack_w(const float* __restrict__ W_ih,
                                              const float* __restrict__ W_hh,
                                              unsigned short* __restrict__ WP,
                                              unsigned int* __restrict__ cnt) {
    if (blockIdx.x == 0 && threadIdx.x < NGRP) cnt[threadIdx.x * 64] = 0u;
    int P = blockIdx.x * 256 + threadIdx.x;  // pair index < 163840
    int L = P * 2;
    int j = L & 7;
    int q = (L >> 3) & 31;
    int v = L >> 8;          // b_loc*40 + i, < 1280
    int i = v % 40;
    int b_loc = v / 40;
    int cs = q >> 2, p = q & 3;
    int ci = i >> 3, gg = (i >> 1) & 3, up = i & 1;
    int R = gg * 256 + b_loc * 8 + p * 2 + up;
    int k = (cs * 5 + ci) * 8 + j;
    float f0, f1;
    if (k < HID) {
        f0 = W_hh[R * HID + k];
        f1 = W_hh[R * HID + k + 1];
    } else {
        f0 = W_ih[R * NUM_CH + k - HID];
        f1 = W_ih[R * NUM_CH + k - HID + 1];
    }
    ((unsigned int*)WP)[P] = pk2(f0, f1);
}

// ---------------------------------------------------------------------------
// NMS (unchanged from round 4: correct, ~tens of µs).
// ---------------------------------------------------------------------------
__global__ __launch_bounds__(1024) void nms_kernel(const float* __restrict__ prop,
                                                   int* __restrict__ t0_out) {
    __shared__ __align__(16) float s_sc[NUM_PROP];
    __shared__ __align__(8) float2 sse[NUM_PROP];
    __shared__ unsigned char sup[NUM_PROP];
    __shared__ unsigned long long cmask[16];

    const int tid = threadIdx.x;
    float ps = prop[tid * 3 + 0];
    float pe = prop[tid * 3 + 1];
    float pc = prop[tid * 3 + 2];
    s_sc[tid] = pc;
    sup[tid] = 0;
    __syncthreads();

    int r = 0;
    const float4* sc4 = (const float4*)s_sc;
    for (int q = 0; q < NUM_PROP / 4; ++q) {
        float4 v = sc4[q];
        int j = q * 4;
        r += (v.x > pc) || (v.x == pc && (j + 0) < tid);
        r += (v.y > pc) || (v.y == pc && (j + 1) < tid);
        r += (v.z > pc) || (v.z == pc && (j + 2) < tid);
        r += (v.w > pc) || (v.w == pc && (j + 3) < tid);
    }
    sse[r] = make_float2(ps, pe);
    __syncthreads();

    const float my_s = sse[tid].x;
    const float my_e = sse[tid].y;
    const float my_len = my_e - my_s;
    bool mysup = false;

    for (int ci = 0; ci < 16; ++ci) {
        if (tid < 64) {
            int i = ci * 64 + tid;
            float2 ie2 = sse[i];
            float is_ = ie2.x, ie_ = ie2.y;
            unsigned long long m = __ballot(sup[i] != 0);
            for (int l = 0; l < 64; ++l) {
                if (!((m >> l) & 1)) {
                    float ls = __shfl(is_, l);
                    float le = __shfl(ie_, l);
                    float inter = fmaxf(fminf(le, ie_) - fmaxf(ls, is_), 0.0f);
                    float uni = (le - ls) + (ie_ - is_) - inter;
                    float iou = inter / fmaxf(uni, 1e-6f);
                    unsigned long long nb = __ballot((tid > l) && (iou > 0.5f));
                    m |= nb;
                }
            }
            sup[i] = (unsigned char)((m >> tid) & 1);
            if (tid == 0) cmask[ci] = ~m;
        }
        __syncthreads();
        unsigned long long am = cmask[ci];
        for (int l = 0; l < 64; ++l) {
            if ((am >> l) & 1) {
                int i = ci * 64 + l;
                if (tid > i && !mysup) {
                    float2 ie2 = sse[i];
                    float inter = fmaxf(fminf(ie2.y, my_e) - fmaxf(ie2.x, my_s), 0.0f);
                    float uni = (ie2.y - ie2.x) + my_len - inter;
                    if (inter / fmaxf(uni, 1e-6f) > 0.5f) mysup = true;
                }
            }
        }
        sup[tid] = mysup ? 1 : 0;
        __syncthreads();
    }

    int myc = tid >> 6;
    unsigned long long mybit = 1ull << (tid & 63);
    int kb = 0, kt = 0;
    for (int c2 = 0; c2 < 16; ++c2) {
        int p = __popcll(cmask[c2]);
        kt += p;
        if (c2 < myc) kb += p;
    }
    kb += __popcll(cmask[myc] & (mybit - 1));
    int slot = (cmask[myc] & mybit) ? kb : (kt + (tid - kb));
    if (slot < NUM_PROP_AFTER) {
        int t0 = (int)rintf(my_s);
        t0 = max(0, min(t0, T_LEN - PROP_LEN));
        t0_out[slot] = t0;
    }
}

// ---------------------------------------------------------------------------
// Persistent-weight cooperative LSTM.
// 256 blocks x 256 threads, 1 block/CU.  Group g = bid&7 (32 blocks, one XCD)
// owns seqs [g*32, g*32+32).  Block b_loc = bid>>3 owns hidden units
// [b_loc*8, b_loc*8+8) => 32 W rows x K=320 = 20 KB f16, register-resident.
// Per step: gate tile from LDS h/x -> LDS k-reduce -> 1 cell/thread epilogue
// -> 512 B h-slice exchange through L2 (atomic arrive + spin) -> restage h.
// ---------------------------------------------------------------------------
__global__ __launch_bounds__(256, 1) void lstm_kernel(
    const float* __restrict__ data, const int* __restrict__ t0s,
    const unsigned short* __restrict__ WP, unsigned int* __restrict__ cnt,
    unsigned short* __restrict__ hglob,
    const float* __restrict__ b_ih, const float* __restrict__ b_hh,
    const float* __restrict__ W_cls, const float* __restrict__ b_cls,
    const float* __restrict__ W_bbox, const float* __restrict__ b_bbox,
    float* __restrict__ out) {
    // hx[s][chunk(40)+pad][8]: stride 41 chosen so dot-phase banks spread (~2-way)
    __shared__ __align__(16) _Float16 hx[32][41][8];        // 21.0 KB
    __shared__ __align__(16) float pacc[8 * 1200 + 64];     // cs-stride 1200, row-stride 37
    __shared__ __align__(16) _Float16 hsl[32][8];           // transpose tile for slice store

    const int tid = threadIdx.x;
    const int g = blockIdx.x & 7;
    const int b_loc = blockIdx.x >> 3;

    // dot-phase mapping: thread = (cs, p, sgrp); seqs s = sgrp + 8*ss (strided!)
    const int cs = tid >> 5;
    const int p = (tid >> 3) & 3;
    const int sgrp = tid & 7;
    // cell mapping (epilogue): unit u_loc, seq s_cell
    const int u_loc = tid >> 5;
    const int s_cell = tid & 31;
    // x-stage mapping
    const int xs = tid >> 3;
    const int xb = tid & 7;

    unsigned int* mycnt = cnt + g * 64;  // 256B-spaced counters

    // --- W prologue: 40 uint4 = 160 VGPR, register-resident for all 128 steps
    uint4 wreg[5][8];
    {
        const uint4* wp4 = (const uint4*)WP;
        const int qq = tid >> 3;  // cs*4+p
#pragma unroll
        for (int ci = 0; ci < 5; ++ci)
#pragma unroll
            for (int r8 = 0; r8 < 8; ++r8)
                wreg[ci][r8] = wp4[(b_loc * 40 + (ci * 8 + r8)) * 32 + qq];
    }

    float bias[4];
    {
        const int u = b_loc * 8 + u_loc;
#pragma unroll
        for (int gg = 0; gg < 4; ++gg)
            bias[gg] = b_ih[gg * 256 + u] + b_hh[gg * 256 + u];
    }

    const int t0_x = t0s[g * 32 + xs];
    const float4* d4 = (const float4*)data;

    // init: h(0)=0, x(0)
#pragma unroll
    for (int k = 0; k < 4; ++k) {
        int n = tid * 4 + k;
        *(uint4*)&hx[n >> 5][n & 31][0] = make_uint4(0, 0, 0, 0);
    }
    {
        float4 f0 = d4[t0_x * 16 + xb * 2];
        float4 f1 = d4[t0_x * 16 + xb * 2 + 1];
        *(uint4*)&hx[xs][32 + xb][0] =
            make_uint4(pk2(f0.x, f0.y), pk2(f0.z, f0.w), pk2(f1.x, f1.y), pk2(f1.z, f1.w));
    }
    float cst = 0.0f;
    __syncthreads();

    for (int t = 0; t < PROP_LEN; ++t) {
        // ---- DOT: acc4[r8] = float4 over ss (seqs sgrp+8*ss)
        float4 acc4[8];
#pragma unroll
        for (int r8 = 0; r8 < 8; ++r8) acc4[r8] = make_float4(0.f, 0.f, 0.f, 0.f);
#pragma unroll
        for (int ci = 0; ci < 5; ++ci) {
            const int c = cs * 5 + ci;
            uint4 hh0 = *(const uint4*)&hx[sgrp][c][0];
            uint4 hh1 = *(const uint4*)&hx[sgrp + 8][c][0];
            uint4 hh2 = *(const uint4*)&hx[sgrp + 16][c][0];
            uint4 hh3 = *(const uint4*)&hx[sgrp + 24][c][0];
#pragma unroll
            for (int r8 = 0; r8 < 8; ++r8) {
                acc4[r8].x = dot8f(wreg[ci][r8], hh0, acc4[r8].x);
                acc4[r8].y = dot8f(wreg[ci][r8], hh1, acc4[r8].y);
                acc4[r8].z = dot8f(wreg[ci][r8], hh2, acc4[r8].z);
                acc4[r8].w = dot8f(wreg[ci][r8], hh3, acc4[r8].w);
            }
        }
        // ---- partial write: float4 per row, idx = cs*1200 + row*37 + sgrp*4
#pragma unroll
        for (int r8 = 0; r8 < 8; ++r8) {
            const int row = (r8 >> 1) * 8 + p * 2 + (r8 & 1);
            *(float4*)&pacc[cs * 1200 + row * 37 + sgrp * 4] = acc4[r8];
        }
        __syncthreads();

        // ---- reduce + gate epilogue: one cell (u_loc, s_cell) per thread
        {
            const int so = (s_cell & 7) * 4 + (s_cell >> 3);
            float gs[4];
#pragma unroll
            for (int gg = 0; gg < 4; ++gg) {
                const int row = gg * 8 + u_loc;
                float a = bias[gg];
#pragma unroll
                for (int c8 = 0; c8 < 8; ++c8) a += pacc[c8 * 1200 + row * 37 + so];
                gs[gg] = a;
            }
            float gi = fsigmoid(gs[0]);
            float gf = fsigmoid(gs[1]);
            float gG = ftanh(gs[2]);
            float go = fsigmoid(gs[3]);
            cst = gf * cst + gi * gG;
            HU16 hv;
            hv.h = (_Float16)(go * ftanh(cst));
            hsl[s_cell][u_loc] = hv.h;
        }
        // issue next-x loads early (independent of LDS phases)
        float4 xf0, xf1;
        const bool has_x = (t < PROP_LEN - 1);
        if (has_x) {
            const int row = t0_x + t + 1;
            xf0 = d4[row * 16 + xb * 2];
            xf1 = d4[row * 16 + xb * 2 + 1];
        }
        __syncthreads();

        const int par = (t + 1) & 1;
        // ---- h-slice store: 32 lanes x 16 B (coalesced into [par][g][s][u])
        if (tid < 32) {
            const uint4 v = *(const uint4*)&hsl[tid][0];
            *(uint4*)&hglob[(par * 8 + g) * 8192 + tid * 256 + b_loc * 8] = v;
        }
        // ---- x(t+1) into LDS (x-region; disjoint from h restage)
        if (has_x) {
            *(uint4*)&hx[xs][32 + xb][0] =
                make_uint4(pk2(xf0.x, xf0.y), pk2(xf0.z, xf0.w),
                           pk2(xf1.x, xf1.y), pk2(xf1.z, xf1.w));
        }
        // ---- arrive + spin (group barrier through L2)
        if (tid == 0) {
            __threadfence();
            __hip_atomic_fetch_add(mycnt, 1u, __ATOMIC_RELEASE, __HIP_MEMORY_SCOPE_AGENT);
            const unsigned tgt = (unsigned)(GBLK * (t + 1));
            while (__hip_atomic_load(mycnt, __ATOMIC_ACQUIRE, __HIP_MEMORY_SCOPE_AGENT) < tgt)
                __builtin_amdgcn_s_sleep(1);
        }
        __syncthreads();
        __threadfence();  // acquire: invalidate stale cached h_glob lines
        // ---- restage full h(t+1): 4 coalesced dwordx4 per thread
        {
            const int s = tid >> 3, part = tid & 7;
            const uint4* src =
                (const uint4*)&hglob[(par * 8 + g) * 8192 + s * 256 + part * 32];
#pragma unroll
            for (int q = 0; q < 4; ++q) {
                uint4 v = src[q];
                *(uint4*)&hx[s][part * 4 + q][0] = v;
            }
        }
        __syncthreads();
    }

    // ---- heads: this block handles seq g*32 + b_loc using hx[b_loc][*]
    if (tid < 120) {
        const int sg = g * 32 + b_loc;
        const float* Wrow;
        float a;
        int oidx;
        if (tid < NUM_CLS) {
            Wrow = W_cls + tid * HID;
            a = b_cls[tid];
            oidx = sg * NUM_CLS + tid;
        } else {
            const int mb = tid - NUM_CLS;
            Wrow = W_bbox + mb * HID;
            a = b_bbox[mb];
            oidx = NUM_PROP_AFTER * NUM_CLS + sg * 2 * NUM_CLS + mb;
        }
        const float4* w4 = (const float4*)Wrow;
        for (int c = 0; c < 32; ++c) {
            uint4 hv = *(const uint4*)&hx[b_loc][c][0];
            U32H2 p0, p1, p2, p3;
            p0.u = hv.x;
            p1.u = hv.y;
            p2.u = hv.z;
            p3.u = hv.w;
            float4 wa = w4[2 * c], wb = w4[2 * c + 1];
            a += (float)p0.h[0] * wa.x + (float)p0.h[1] * wa.y +
                 (float)p1.h[0] * wa.z + (float)p1.h[1] * wa.w +
                 (float)p2.h[0] * wb.x + (float)p2.h[1] * wb.y +
                 (float)p3.h[0] * wb.z + (float)p3.h[1] * wb.w;
        }
        out[oidx] = a;
    }
}

extern "C" void kernel_launch(void* const* d_in, const int* in_sizes, int n_in,
                              void* d_out, int out_size, void* d_ws,
                              size_t ws_size, hipStream_t stream) {
    const float* data = (const float*)d_in[0];
    const float* prop = (const float*)d_in[1];
    const float* W_ih = (const float*)d_in[2];
    const float* W_hh = (const float*)d_in[3];
    const float* b_ih = (const float*)d_in[4];
    const float* b_hh = (const float*)d_in[5];
    const float* W_cls = (const float*)d_in[6];
    const float* b_cls = (const float*)d_in[7];
    const float* W_bbox = (const float*)d_in[8];
    const float* b_bbox = (const float*)d_in[9];
    float* out = (float*)d_out;

    unsigned int* cnt = (unsigned int*)d_ws;
    int* t0s = (int*)((char*)d_ws + 2048);
    unsigned short* WP = (unsigned short*)((char*)d_ws + 4096);
    unsigned short* hglob = (unsigned short*)((char*)d_ws + 659456);

    pack_w<<<640, 256, 0, stream>>>(W_ih, W_hh, WP, cnt);
    nms_kernel<<<1, 1024, 0, stream>>>(prop, t0s);

    void* args[] = {&data, &t0s,  &WP,     &cnt,   &hglob, &b_ih,
                    &b_hh, &W_cls, &b_cls, &W_bbox, &b_bbox, &out};
    hipLaunchCooperativeKernel((void*)lstm_kernel, dim3(NBLK), dim3(256), args, 0,
                               stream);
}

// Round 7
// 3683.191 us; speedup vs baseline: 1.1608x; 1.1608x over previous
//
#include <hip/hip_runtime.h>
#include <math.h>

#define T_LEN 8192
#define NUM_CH 64
#define HID 256
#define NUM_CLS 40
#define NUM_PROP 1024
#define NUM_PROP_AFTER 256
#define PROP_LEN 128
#define NQUAD 64              // quads; quad owns 4 sequences
#define QM 4                  // blocks (members) per quad; member owns 64 units
#define NBLK (NQUAD * QM)     // 256 blocks, 1 per CU
#define WPITCH 260            // wlds row pitch in halves (520 B: 8B-aligned, 4-way)

typedef _Float16 h2_t __attribute__((ext_vector_type(2)));
union U32H2 { unsigned int u; h2_t h; };
union HU16 { _Float16 h; unsigned short u; };

#if defined(__has_builtin)
#if __has_builtin(__builtin_amdgcn_fdot2)
#define HAS_FDOT2 1
#endif
#endif

__device__ __forceinline__ float dot2f(unsigned int wa, unsigned int hb, float acc) {
    U32H2 a, b;
    a.u = wa;
    b.u = hb;
#ifdef HAS_FDOT2
    return __builtin_amdgcn_fdot2(a.h, b.h, acc, false);
#else
    return acc + (float)a.h[0] * (float)b.h[0] + (float)a.h[1] * (float)b.h[1];
#endif
}

__device__ __forceinline__ float dot8f(const uint4& w, const uint4& h, float acc) {
    acc = dot2f(w.x, h.x, acc);
    acc = dot2f(w.y, h.y, acc);
    acc = dot2f(w.z, h.z, acc);
    acc = dot2f(w.w, h.w, acc);
    return acc;
}

__device__ __forceinline__ float fsigmoid(float x) { return 1.0f / (1.0f + __expf(-x)); }
__device__ __forceinline__ float ftanh(float x) {
    float e = __expf(-2.0f * fabsf(x));
    float t = (1.0f - e) / (1.0f + e);
    return copysignf(t, x);
}

// ---------------------------------------------------------------------------
// Workspace layout (bytes):
//   0      : quad arrive counters, 64 x 64 B
//   4096   : t0s (256 int)
//   8192   : WP  f16 W_hh, block-contiguous: [m][row_loc][k]  (512 KB)
//   532480 : WI  f16 W_ih, [row][k] identity                  (128 KB)
//   663552 : hglob [2 parity][256 seq][256 unit] halves       (256 KB)
// ---------------------------------------------------------------------------

// Pack weights to f16.  WP half-index e = ((m*256 + rl)*32 + c)*8 + j with
// rl = g*64 + ul -> source row r = g*256 + m*64 + ul, col k = c*8+j.
// WI is identity-layout f16 of W_ih.  Also zeroes the quad counters.
__global__ __launch_bounds__(256) void pack_w(const float* __restrict__ W_ih,
                                              const float* __restrict__ W_hh,
                                              unsigned short* __restrict__ WP,
                                              unsigned short* __restrict__ WI,
                                              unsigned int* __restrict__ cnt) {
    if (blockIdx.x == 0 && threadIdx.x < NQUAD) cnt[threadIdx.x * 16] = 0u;
    int e = blockIdx.x * 256 + threadIdx.x;  // 0 .. 327679
    HU16 hv;
    if (e < 262144) {
        int j = e & 7;
        int c = (e >> 3) & 31;
        int rl = (e >> 8) & 255;
        int m = e >> 16;
        int g = rl >> 6, ul = rl & 63;
        int r = g * 256 + m * 64 + ul;
        hv.h = (_Float16)W_hh[r * HID + c * 8 + j];
        WP[e] = hv.u;
    } else {
        int e2 = e - 262144;  // < 65536
        hv.h = (_Float16)W_ih[e2];
        WI[e2] = hv.u;
    }
}

// ---------------------------------------------------------------------------
// NMS (unchanged since round 4; correct).
// ---------------------------------------------------------------------------
__global__ __launch_bounds__(1024) void nms_kernel(const float* __restrict__ prop,
                                                   int* __restrict__ t0_out) {
    __shared__ __align__(16) float s_sc[NUM_PROP];
    __shared__ __align__(8) float2 sse[NUM_PROP];
    __shared__ unsigned char sup[NUM_PROP];
    __shared__ unsigned long long cmask[16];

    const int tid = threadIdx.x;
    float ps = prop[tid * 3 + 0];
    float pe = prop[tid * 3 + 1];
    float pc = prop[tid * 3 + 2];
    s_sc[tid] = pc;
    sup[tid] = 0;
    __syncthreads();

    int r = 0;
    const float4* sc4 = (const float4*)s_sc;
    for (int q = 0; q < NUM_PROP / 4; ++q) {
        float4 v = sc4[q];
        int j = q * 4;
        r += (v.x > pc) || (v.x == pc && (j + 0) < tid);
        r += (v.y > pc) || (v.y == pc && (j + 1) < tid);
        r += (v.z > pc) || (v.z == pc && (j + 2) < tid);
        r += (v.w > pc) || (v.w == pc && (j + 3) < tid);
    }
    sse[r] = make_float2(ps, pe);
    __syncthreads();

    const float my_s = sse[tid].x;
    const float my_e = sse[tid].y;
    const float my_len = my_e - my_s;
    bool mysup = false;

    for (int ci = 0; ci < 16; ++ci) {
        if (tid < 64) {
            int i = ci * 64 + tid;
            float2 ie2 = sse[i];
            float is_ = ie2.x, ie_ = ie2.y;
            unsigned long long m = __ballot(sup[i] != 0);
            for (int l = 0; l < 64; ++l) {
                if (!((m >> l) & 1)) {
                    float ls = __shfl(is_, l);
                    float le = __shfl(ie_, l);
                    float inter = fmaxf(fminf(le, ie_) - fmaxf(ls, is_), 0.0f);
                    float uni = (le - ls) + (ie_ - is_) - inter;
                    float iou = inter / fmaxf(uni, 1e-6f);
                    unsigned long long nb = __ballot((tid > l) && (iou > 0.5f));
                    m |= nb;
                }
            }
            sup[i] = (unsigned char)((m >> tid) & 1);
            if (tid == 0) cmask[ci] = ~m;
        }
        __syncthreads();
        unsigned long long am = cmask[ci];
        for (int l = 0; l < 64; ++l) {
            if ((am >> l) & 1) {
                int i = ci * 64 + l;
                if (tid > i && !mysup) {
                    float2 ie2 = sse[i];
                    float inter = fmaxf(fminf(ie2.y, my_e) - fmaxf(ie2.x, my_s), 0.0f);
                    float uni = (ie2.y - ie2.x) + my_len - inter;
                    if (inter / fmaxf(uni, 1e-6f) > 0.5f) mysup = true;
                }
            }
        }
        sup[tid] = mysup ? 1 : 0;
        __syncthreads();
    }

    int myc = tid >> 6;
    unsigned long long mybit = 1ull << (tid & 63);
    int kb = 0, kt = 0;
    for (int c2 = 0; c2 < 16; ++c2) {
        int p = __popcll(cmask[c2]);
        kt += p;
        if (c2 < myc) kb += p;
    }
    kb += __popcll(cmask[myc] & (mybit - 1));
    int slot = (cmask[myc] & mybit) ? kb : (kt + (tid - kb));
    if (slot < NUM_PROP_AFTER) {
        int t0 = (int)rintf(my_s);
        t0 = max(0, min(t0, T_LEN - PROP_LEN));
        t0_out[slot] = t0;
    }
}

// ---------------------------------------------------------------------------
// Quad-cooperative LSTM.  256 blocks x 256 threads, 1 block/CU (cooperative
// launch).  Quad q = bid&63 owns seqs q*4..q*4+3; member m = bid>>6 owns
// units m*64..m*64+64 (all 4 gates).  Members of a quad share bid&7 -> same
// XCD under the round-robin dispatch heuristic (perf-only assumption).
// W_hh slice (256 rows x K=256 f16 = 128 KB) lives in LDS, staged once.
// W_ih row per thread in 8 uint4 (32 VGPR).  No register W arrays -> no
// spill.  Per step: full-K dots -> gates via LDS -> 1-cell/thread epilogue
// -> 512 B h-slice exchange through L2 (fence/atomic/spin) -> restage 4 KB.
// ---------------------------------------------------------------------------
__global__ __launch_bounds__(256, 1) void lstm_kernel(
    const float* __restrict__ data, const int* __restrict__ t0s,
    const unsigned short* __restrict__ WP, const unsigned short* __restrict__ WI,
    unsigned int* __restrict__ cnt, unsigned short* __restrict__ hglob,
    const float* __restrict__ b_ih, const float* __restrict__ b_hh,
    const float* __restrict__ W_cls, const float* __restrict__ b_cls,
    const float* __restrict__ W_bbox, const float* __restrict__ b_bbox,
    float* __restrict__ out) {
    __shared__ __align__(16) _Float16 wlds[256 * WPITCH];  // 133,120 B
    __shared__ __align__(16) _Float16 hbuf[4][40][8];      // 2,560 B (h + x chunks)
    __shared__ float gates[4 * 64 * 5];                    // 5,120 B, pitch-5

    const int tid = threadIdx.x;
    const int q = blockIdx.x & 63;
    const int m = blockIdx.x >> 6;
    const int g = tid >> 6;   // gate (dot phase)
    const int ul = tid & 63;  // unit local
    const int row_loc = tid;  // g*64 + ul
    const int es = tid >> 6;  // seq (epilogue + x phases)
    const int eu = ul;

    unsigned int* mycnt = cnt + q * 16;

    // ---- stage W_hh slice: 128 KB contiguous from WP[m], 32 iters
    {
        const uint4* wp4 = (const uint4*)WP + m * 8192;
        for (int i = 0; i < 32; ++i) {
            int idx = i * 256 + tid;
            int rl = idx >> 5, c = idx & 31;
            uint4 v = wp4[idx];
            _Float16* dst = &wlds[rl * WPITCH + c * 8];
            *(uint2*)dst = make_uint2(v.x, v.y);
            *(uint2*)(dst + 4) = make_uint2(v.z, v.w);
        }
    }
    // ---- W_ih row of my gate-row into registers (8 uint4 = 32 VGPR)
    uint4 wih[8];
    {
        const int r = g * 256 + m * 64 + ul;
        const uint4* wi4 = (const uint4*)WI;
#pragma unroll
        for (int p = 0; p < 8; ++p) wih[p] = wi4[r * 8 + p];
    }
    const float bias =
        b_ih[g * 256 + m * 64 + ul] + b_hh[g * 256 + m * 64 + ul];

    const int t0x = t0s[q * 4 + es];

    // ---- init hbuf: h(0)=0 (chunks 0..31), x(0) (chunks 32..39)
    if (tid < 128) {
        int s = tid >> 5, c = tid & 31;
        *(uint4*)&hbuf[s][c][0] = make_uint4(0, 0, 0, 0);
    }
    {
        HU16 hv;
        hv.h = (_Float16)data[t0x * NUM_CH + eu];
        hbuf[es][32 + (eu >> 3)][eu & 7] = hv.h;
    }
    float cst = 0.0f;  // cell state of (seq es, unit m*64+eu)
    __syncthreads();

    for (int t = 0; t < PROP_LEN; ++t) {
        // next x issued early (global, hidden under dot phase)
        float xnext = 0.0f;
        if (t < PROP_LEN - 1) xnext = data[(t0x + t + 1) * NUM_CH + eu];

        float a0 = bias, a1 = bias, a2 = bias, a3 = bias;
#pragma unroll
        for (int c = 0; c < 40; ++c) {
            uint4 w;
            if (c < 32) {
                const _Float16* wp = &wlds[row_loc * WPITCH + c * 8];
                uint2 lo = *(const uint2*)wp;
                uint2 hi = *(const uint2*)(wp + 4);
                w = make_uint4(lo.x, lo.y, hi.x, hi.y);
            } else {
                w = wih[c - 32];
            }
            a0 = dot8f(w, *(const uint4*)&hbuf[0][c][0], a0);
            a1 = dot8f(w, *(const uint4*)&hbuf[1][c][0], a1);
            a2 = dot8f(w, *(const uint4*)&hbuf[2][c][0], a2);
            a3 = dot8f(w, *(const uint4*)&hbuf[3][c][0], a3);
        }
        gates[row_loc * 5 + 0] = a0;
        gates[row_loc * 5 + 1] = a1;
        gates[row_loc * 5 + 2] = a2;
        gates[row_loc * 5 + 3] = a3;
        __syncthreads();  // (A) dot phase complete

        const int par = (t + 1) & 1;
        // epilogue: cell (es, m*64+eu)
        {
            float gi = fsigmoid(gates[(0 * 64 + eu) * 5 + es]);
            float gf = fsigmoid(gates[(1 * 64 + eu) * 5 + es]);
            float gg = ftanh(gates[(2 * 64 + eu) * 5 + es]);
            float go = fsigmoid(gates[(3 * 64 + eu) * 5 + es]);
            cst = gf * cst + gi * gg;
            HU16 hv;
            hv.h = (_Float16)(go * ftanh(cst));
            hglob[(par * 256 + q * 4 + es) * 256 + m * 64 + eu] = hv.u;
        }
        if (t < PROP_LEN - 1) {
            HU16 hv;
            hv.h = (_Float16)xnext;
            hbuf[es][32 + (eu >> 3)][eu & 7] = hv.h;
        }
        __syncthreads();  // (B) all stores issued+drained (vmcnt) block-wide

        if (tid == 0) {
            __threadfence();
            __hip_atomic_fetch_add(mycnt, 1u, __ATOMIC_RELEASE,
                                   __HIP_MEMORY_SCOPE_AGENT);
            const unsigned tgt = (unsigned)(QM * (t + 1));
            while (__hip_atomic_load(mycnt, __ATOMIC_ACQUIRE,
                                     __HIP_MEMORY_SCOPE_AGENT) < tgt)
                __builtin_amdgcn_s_sleep(1);
        }
        __syncthreads();  // (C)
        __threadfence();  // invalidate stale L1 lines before peer reads

        if (tid < 128) {  // restage full h(t+1): 4 KB, coalesced uint4
            int s = tid >> 5, c = tid & 31;
            uint4 v = *(const uint4*)&hglob[(par * 256 + q * 4 + s) * 256 + c * 8];
            *(uint4*)&hbuf[s][c][0] = v;
        }
        __syncthreads();  // (D)
    }

    // ---- heads: this block -> seq q*4 + m, h in hbuf[m]
    if (tid < 120) {
        const int sg = q * 4 + m;
        const float* Wrow;
        float a;
        int oidx;
        if (tid < NUM_CLS) {
            Wrow = W_cls + tid * HID;
            a = b_cls[tid];
            oidx = sg * NUM_CLS + tid;
        } else {
            const int mb = tid - NUM_CLS;
            Wrow = W_bbox + mb * HID;
            a = b_bbox[mb];
            oidx = NUM_PROP_AFTER * NUM_CLS + sg * 2 * NUM_CLS + mb;
        }
        const float4* w4 = (const float4*)Wrow;
        for (int c = 0; c < 32; ++c) {
            uint4 hv = *(const uint4*)&hbuf[m][c][0];
            U32H2 p0, p1, p2, p3;
            p0.u = hv.x;
            p1.u = hv.y;
            p2.u = hv.z;
            p3.u = hv.w;
            float4 wa = w4[2 * c], wb = w4[2 * c + 1];
            a += (float)p0.h[0] * wa.x + (float)p0.h[1] * wa.y +
                 (float)p1.h[0] * wa.z + (float)p1.h[1] * wa.w +
                 (float)p2.h[0] * wb.x + (float)p2.h[1] * wb.y +
                 (float)p3.h[0] * wb.z + (float)p3.h[1] * wb.w;
        }
        out[oidx] = a;
    }
}

extern "C" void kernel_launch(void* const* d_in, const int* in_sizes, int n_in,
                              void* d_out, int out_size, void* d_ws,
                              size_t ws_size, hipStream_t stream) {
    const float* data = (const float*)d_in[0];
    const float* prop = (const float*)d_in[1];
    const float* W_ih = (const float*)d_in[2];
    const float* W_hh = (const float*)d_in[3];
    const float* b_ih = (const float*)d_in[4];
    const float* b_hh = (const float*)d_in[5];
    const float* W_cls = (const float*)d_in[6];
    const float* b_cls = (const float*)d_in[7];
    const float* W_bbox = (const float*)d_in[8];
    const float* b_bbox = (const float*)d_in[9];
    float* out = (float*)d_out;

    unsigned int* cnt = (unsigned int*)d_ws;
    int* t0s = (int*)((char*)d_ws + 4096);
    unsigned short* WP = (unsigned short*)((char*)d_ws + 8192);
    unsigned short* WI = (unsigned short*)((char*)d_ws + 532480);
    unsigned short* hglob = (unsigned short*)((char*)d_ws + 663552);

    pack_w<<<1280, 256, 0, stream>>>(W_ih, W_hh, WP, WI, cnt);
    nms_kernel<<<1, 1024, 0, stream>>>(prop, t0s);

    void* args[] = {&data,  &t0s,   &WP,    &WI,     &cnt,    &hglob, &b_ih,
                    &b_hh,  &W_cls, &b_cls, &W_bbox, &b_bbox, &out};
    hipLaunchCooperativeKernel((void*)lstm_kernel, dim3(NBLK), dim3(256), args,
                               0, stream);
}